// Round 7
// baseline (256.685 us; speedup 1.0000x reference)
//
#include <hip/hip_runtime.h>
#include <hip/hip_bf16.h>

// B=4, T=2048, H=1024, NH=16, HD=64. Inputs FP32, output FP32.
// R16: QKV GEMM ported to the 256^2 8-phase template (T2+T3+T4+T5):
//  - BM=BN=256, BK=64, 8 waves (2Mx4N), per-wave C 128x64 in 4 quadrants
//    (A-half=q&1, B-half=q>>1 -> phase-localized reads).
//  - half-tile h of K-tile T staged at phase 4T-6+h, order {B0,A0,A1,B1};
//    counted s_waitcnt vmcnt(4) ONLY at phases 4/8 (vmcnt(0) last iter);
//    raw s_barrier x2 per phase; setprio(1) around the 16-MFMA cluster.
//  - LDS 128 KiB (2 dbuf x A/B x 2 half x 128x64 bf16), 1 block/CU.
//  - XOR chunk swizzle (row&7) on stage source + frag reads (R5-verified).
// gemm1 stays on the 128^2 2-phase kernel (N=1024 -> only 128 blocks at
// 256^2). Attn / casts / transpose unchanged from R6.

typedef unsigned short ushort_t;
typedef __attribute__((ext_vector_type(8))) short  s8v;
typedef __attribute__((ext_vector_type(4))) float  f4v;
typedef __attribute__((ext_vector_type(4))) unsigned int u4v;

__device__ inline ushort_t f2bf(float f) {
    unsigned u = __builtin_bit_cast(unsigned, f);
    u += 0x7fffu + ((u >> 16) & 1u);   // RNE
    return (ushort_t)(u >> 16);
}

// async global->LDS, 16B per lane; LDS dest must be wave-uniform base + lane*16
__device__ inline void gload16(const ushort_t* g, ushort_t* l) {
    __builtin_amdgcn_global_load_lds(
        (const __attribute__((address_space(1))) unsigned int*)g,
        (__attribute__((address_space(3))) unsigned int*)l, 16, 0, 0);
}

__global__ __launch_bounds__(256) void cast_f32_bf16(
    const float* __restrict__ in, ushort_t* __restrict__ out, int n8)
{
    int i = blockIdx.x * 256 + threadIdx.x;
    if (i >= n8) return;
    const float* p = in + (size_t)i * 8;
    f4v a = *(const f4v*)p;
    f4v b = *(const f4v*)(p + 4);
    union { u4v v; ushort_t u[8]; } o;
    #pragma unroll
    for (int j = 0; j < 4; j++) { o.u[j] = f2bf(a[j]); o.u[j + 4] = f2bf(b[j]); }
    *(u4v*)(out + (size_t)i * 8) = o.v;
}

// ---------------------------------------------------------------------------
// V transpose: in [bh][2048][64] (t-major) -> out [bh][64][2048] (d-major),
// with keys sigma-permuted within each 64-block to match the packed P layout:
// sigma position s -> key k = (s>>5)*32 + (s&1)*16 + ((s&31)>>1).
// ---------------------------------------------------------------------------
__global__ __launch_bounds__(256) void transpose_v(
    const ushort_t* __restrict__ in, ushort_t* __restrict__ out)
{
    const int t0 = blockIdx.x * 64;
    const int bh = blockIdx.y;
    const ushort_t* src = in  + ((size_t)bh * 2048 + t0) * 64;
    ushort_t*       dst = out + (size_t)bh * 64 * 2048 + t0;
    __shared__ __align__(16) ushort_t L[64 * 72];   // [t][72]
    const int tid = threadIdx.x;

    #pragma unroll
    for (int j = 0; j < 2; j++) {
        int c = tid + j * 256;            // 0..511
        int t = c >> 3, d0 = (c & 7) * 8;
        *(s8v*)&L[t * 72 + d0] = *(const s8v*)(src + (size_t)t * 64 + d0);
    }
    __syncthreads();
    #pragma unroll
    for (int j = 0; j < 2; j++) {
        int c = tid + j * 256;
        int d = c >> 3, sp0 = (c & 7) * 8;
        union { s8v v; ushort_t u[8]; } o;
        #pragma unroll
        for (int i = 0; i < 8; i++) {
            int sp = sp0 + i;             // sigma position 0..63
            int sl = sp & 31;
            int k  = (sp >> 5) * 32 + (sl & 1) * 16 + (sl >> 1);
            o.u[i] = L[k * 72 + d];
        }
        *(s8v*)(dst + (size_t)d * 2048 + sp0) = o.v;
    }
}

// ---------------------------------------------------------------------------
// QKV GEMM, 256^2 8-phase. C[8192,3072] = xb[8192,1024] * wqkv[3072,1024]^T.
// Each 256-wide N-tile lies entirely in Q, K, or V (3072 = 3*1024; 12 tiles).
// ---------------------------------------------------------------------------
__global__ __launch_bounds__(512, 2) void gemm256_qkv(
    const ushort_t* __restrict__ A, const ushort_t* __restrict__ Bm,
    ushort_t* __restrict__ o0, ushort_t* __restrict__ o1, ushort_t* __restrict__ o2)
{
    // [dbuf][op A=0/B=1][half][128*64 bf16] = 128 KiB
    __shared__ __align__(16) ushort_t Ls[2][2][2][8192];

    const int tid  = threadIdx.x;
    const int m0   = blockIdx.x * 256;
    const int n0   = blockIdx.y * 256;
    const int wave = tid >> 6, lane = tid & 63;
    const int wm = wave >> 2, wn = wave & 3;       // 2M x 4N wave grid
    const int lhi = lane >> 4, llo = lane & 15;
    const int xs  = llo & 7;                       // read-side XOR

    // stage half-tile: role 0=B0, 1=A0, 2=A1, 3=B1 (order within a K-tile)
    auto stage = [&](int tile, int role) {
        const int d    = tile & 1;
        const int op   = (role == 1 || role == 2) ? 0 : 1;
        const int half = (role >= 2) ? 1 : 0;
        const ushort_t* base = op ? Bm : A;
        const int r0 = op ? n0 : m0;
        #pragma unroll
        for (int rr = 0; rr < 2; rr++) {
            int row = wave * 8 + (lane >> 3) + rr * 64;        // 0..127
            int gch = ((lane & 7) ^ (row & 7)) * 8;            // pre-swizzled
            gload16(base + (size_t)(r0 + half * 128 + row) * 1024 + tile * 64 + gch,
                    &Ls[d][op][half][row * 64 + (lane & 7) * 8]);
        }
    };

    f4v acc[2][2][4][2] = {};   // [qa][qb][i][j], 32 frags = 128 VGPR

    // prologue: serials 0..5 = {B0,A0,A1,B1}(t0), {B0,A0}(t1)
    stage(0, 0); stage(0, 1); stage(0, 2); stage(0, 3);
    stage(1, 0); stage(1, 1);
    asm volatile("s_waitcnt vmcnt(4)" ::: "memory");   // tile 0 landed
    __builtin_amdgcn_s_barrier();

#define GPHASE(D, QA, QB, ST, SR, VM) do {                                       \
    s8v af[4][2], bf[2][2];                                                      \
    _Pragma("unroll")                                                            \
    for (int i = 0; i < 4; i++)                                                  \
      _Pragma("unroll")                                                          \
      for (int s = 0; s < 2; s++)                                                \
        af[i][s] = *(const s8v*)&Ls[D][0][QA][(wm*64 + i*16 + llo)*64 + ((s*4 + lhi) ^ xs)*8]; \
    _Pragma("unroll")                                                            \
    for (int j = 0; j < 2; j++)                                                  \
      _Pragma("unroll")                                                          \
      for (int s = 0; s < 2; s++)                                                \
        bf[j][s] = *(const s8v*)&Ls[D][1][QB][(wn*32 + j*16 + llo)*64 + ((s*4 + lhi) ^ xs)*8]; \
    if ((ST) < 16) stage((ST), (SR));                                            \
    __builtin_amdgcn_s_barrier();                                                \
    __builtin_amdgcn_s_setprio(1);                                               \
    _Pragma("unroll")                                                            \
    for (int s = 0; s < 2; s++)                                                  \
      _Pragma("unroll")                                                          \
      for (int i = 0; i < 4; i++)                                                \
        _Pragma("unroll")                                                        \
        for (int j = 0; j < 2; j++)                                              \
          acc[QA][QB][i][j] = __builtin_amdgcn_mfma_f32_16x16x32_bf16(af[i][s], bf[j][s], acc[QA][QB][i][j], 0, 0, 0); \
    __builtin_amdgcn_s_setprio(0);                                               \
    if ((VM) == 4)      asm volatile("s_waitcnt vmcnt(4)" ::: "memory");         \
    else if ((VM) == 0) asm volatile("s_waitcnt vmcnt(0)" ::: "memory");         \
    __builtin_amdgcn_s_barrier();                                                \
  } while (0)

    #pragma unroll 1
    for (int it = 0; it < 8; ++it) {
        const int s1 = it * 2 + 1, s2 = it * 2 + 2, s3 = it * 2 + 3;
        const int vm = (it == 7) ? 0 : 4;
        // tile 2it (dbuf 0), quadrants (qa,qb) = (0,0)(1,0)(0,1)(1,1)
        GPHASE(0, 0, 0, s1, 2, -1);
        GPHASE(0, 1, 0, s1, 3, -1);
        GPHASE(0, 0, 1, s2, 0, -1);
        GPHASE(0, 1, 1, s2, 1, vm);
        // tile 2it+1 (dbuf 1)
        GPHASE(1, 0, 0, s2, 2, -1);
        GPHASE(1, 1, 0, s2, 3, -1);
        GPHASE(1, 0, 1, s3, 0, -1);
        GPHASE(1, 1, 1, s3, 1, vm);
    }
#undef GPHASE

    // epilogue: scatter Q / K / V (t-major). n-tile uniform per block.
    #pragma unroll
    for (int qa = 0; qa < 2; qa++)
    #pragma unroll
    for (int qb = 0; qb < 2; qb++)
    #pragma unroll
    for (int i = 0; i < 4; i++)
    #pragma unroll
    for (int j = 0; j < 2; j++)
        #pragma unroll
        for (int r = 0; r < 4; r++) {
            int m = m0 + qa * 128 + wm * 64 + i * 16 + lhi * 4 + r;
            int n = n0 + qb * 128 + wn * 32 + j * 16 + llo;
            float val = acc[qa][qb][i][j][r];
            int b  = m >> 11, t = m & 2047;
            int which = n >> 10, hh = n & 1023;
            int head = hh >> 6, d = hh & 63;
            size_t bh = (size_t)(b * 16 + head);
            if (which == 0)
                // Q pre-scaled by 1/sqrt(64)*log2(e) for exp2 softmax
                o0[(size_t)m * 1024 + hh] = f2bf(val * 0.18033688011112042f);
            else {
                ushort_t* dst = (which == 1) ? o1 : o2;
                dst[(bh * 2048 + t) * 64 + d] = f2bf(val);
            }
        }
}

// ---------------------------------------------------------------------------
// GEMM C[M,N] = A[M,K]*B[N,K]^T, K=1024, bf16 MFMA, f32 acc. 128^2, BK=32,
// 2-buffer ping-pong, conflict-free swizzle. Used for the out-projection.
// MODE 1: row-major FP32 store.
// ---------------------------------------------------------------------------
template<int MODE>
__global__ __launch_bounds__(256) void gemm_nt(
    const ushort_t* __restrict__ A, const ushort_t* __restrict__ Bm,
    ushort_t* __restrict__ o0, ushort_t* __restrict__ o1, ushort_t* __restrict__ o2,
    float* __restrict__ of)
{
    __shared__ __align__(16) ushort_t As[2][4096];   // [buf][128][32], chunk-swz
    __shared__ __align__(16) ushort_t Bs[2][4096];

    const int tid  = threadIdx.x;
    const int m0   = blockIdx.x * 128;
    const int n0   = blockIdx.y * 128;
    const int wave = tid >> 6, lane = tid & 63;
    const int wr = wave >> 1, wc = wave & 1;
    const int lhi = lane >> 4, llo = lane & 15;
    const int srow = lane >> 2;
    const int scol = (((lane & 3) ^ ((srow >> 1) & 3)) * 8);

    auto stage = [&](int k0, int buf) {
        #pragma unroll
        for (int p = 0; p < 2; p++) {
            int chunk = wave * 2 + p;                     // 0..7, 16 rows each
            int row = chunk * 16 + srow;
            gload16(A  + (size_t)(m0 + row) * 1024 + k0 + scol,
                    &As[buf][chunk * 512 + lane * 8]);
            gload16(Bm + (size_t)(n0 + row) * 1024 + k0 + scol,
                    &Bs[buf][chunk * 512 + lane * 8]);
        }
    };

    f4v acc[4][4] = {};
    int buf = 0;

    stage(0, 0);
    __syncthreads();

    for (int k0 = 0; k0 < 1024; k0 += 32) {
        if (k0 + 32 < 1024) stage(k0 + 32, buf ^ 1);

        const int rch = (lhi ^ ((llo >> 1) & 3)) * 8;
        s8v a[4], b[4];
        #pragma unroll
        for (int i = 0; i < 4; i++)
            a[i] = *(const s8v*)&As[buf][(wr * 64 + i * 16 + llo) * 32 + rch];
        #pragma unroll
        for (int i = 0; i < 4; i++)
            b[i] = *(const s8v*)&Bs[buf][(wc * 64 + i * 16 + llo) * 32 + rch];
        #pragma unroll
        for (int i = 0; i < 4; i++)
            #pragma unroll
            for (int j = 0; j < 4; j++)
                acc[i][j] = __builtin_amdgcn_mfma_f32_16x16x32_bf16(a[i], b[j], acc[i][j], 0, 0, 0);

        __syncthreads();
        buf ^= 1;
    }

    #pragma unroll
    for (int i = 0; i < 4; i++) {
        #pragma unroll
        for (int j = 0; j < 4; j++) {
            #pragma unroll
            for (int r = 0; r < 4; r++) {
                int m = m0 + wr * 64 + i * 16 + lhi * 4 + r;
                int n = n0 + wc * 64 + j * 16 + llo;
                if (MODE == 1) {
                    of[(size_t)m * 1024 + n] = acc[i][j][r];
                } else {
                    float val = acc[i][j][r];
                    int b  = m >> 11, t = m & 2047;
                    int which = n >> 10, hh = n & 1023;
                    int head = hh >> 6, d = hh & 63;
                    size_t bh = (size_t)(b * 16 + head);
                    if (which == 0)
                        o0[(size_t)m * 1024 + hh] = f2bf(val * 0.18033688011112042f);
                    else {
                        ushort_t* dst = (which == 1) ? o1 : o2;
                        dst[(bh * 2048 + t) * 64 + d] = f2bf(val);
                    }
                }
            }
        }
    }
}

// ---------------------------------------------------------------------------
// Flash attention, causal, exp2 domain, m-free softmax (unchanged from R6).
// ---------------------------------------------------------------------------
__global__ __launch_bounds__(512, 4) void attn_kernel(
    const ushort_t* __restrict__ q_ws, const ushort_t* __restrict__ k_ws,
    const ushort_t* __restrict__ v_ws, ushort_t* __restrict__ ao_ws)
{
    const int p    = blockIdx.x;          // 0..7 -> q-tiles (p, 15-p)
    const int bh   = blockIdx.y;
    const int tid  = threadIdx.x;
    const int wave = tid >> 6, lane = tid & 63;
    const int lhi = lane >> 4, llo = lane & 15;
    const int b = bh >> 4, head = bh & 15;

    const ushort_t* Kb = k_ws + (size_t)bh * 2048 * 64;
    const ushort_t* Vb = v_ws + (size_t)bh * 64 * 2048;   // [d][sigma(t)]

    __shared__ __align__(16) ushort_t Ks [2][4096];       // [buf][64 kk][64 d] swz
    __shared__ __align__(16) ushort_t Vts[2][4096];       // [buf][64 d][64 sig] swz
    __shared__ __align__(16) ushort_t Ps [8][2][1280];    // [wave][g][half][16q][40]

    const int srow = wave * 8 + (lane >> 3);              // 0..63
    const int gch  = ((lane & 7) ^ (srow & 7)) * 8;       // pre-swizzled src col
    auto stage = [&](int t, int buf) {
        const int kk0 = t * 64;
        gload16(Kb + (size_t)(kk0 + srow) * 64 + gch,
                &Ks[buf][srow * 64 + (lane & 7) * 8]);
        gload16(Vb + (size_t)srow * 2048 + kk0 + gch,
                &Vts[buf][srow * 64 + (lane & 7) * 8]);
    };

    const int qt  = (wave >> 2) ? (15 - p) : p;           // this wave's q-tile
    const int wq0 = qt * 128 + (wave & 3) * 32;           // wave's 32 q-rows

    s8v qf[2][2];
    #pragma unroll
    for (int g = 0; g < 2; g++) {
        const ushort_t* Qp = q_ws + (size_t)(b * 2048 + wq0 + g * 16 + llo) * 1024 + head * 64;
        qf[g][0] = *(const s8v*)(Qp + lhi * 8);
        qf[g][1] = *(const s8v*)(Qp + 32 + lhi * 8);
    }

    f4v o[2][4] = {};
    float lsum[2][4] = {};

    const int ntb = 32 - 2 * p;           // shared loop length
    const int xs  = llo & 7;
    int cur = 0;

    stage(0, 0);
    __syncthreads();

    #pragma unroll 1
    for (int t = 0; t < ntb; t++) {
        if (t + 1 < ntb) stage(t + 1, cur ^ 1);

        const int kk0 = t * 64;
        if (kk0 <= wq0 + 31) {
            f4v s0[4], s1[4];
            #pragma unroll
            for (int c = 0; c < 4; c++) {
                const int rb = (c * 16 + llo) * 64;
                s8v kb0 = *(const s8v*)&Ks[cur][rb + ((lhi    ) ^ xs) * 8];
                s8v kb1 = *(const s8v*)&Ks[cur][rb + ((4 + lhi) ^ xs) * 8];
                f4v z0 = {}, z1 = {};
                z0 = __builtin_amdgcn_mfma_f32_16x16x32_bf16(qf[0][0], kb0, z0, 0, 0, 0);
                z0 = __builtin_amdgcn_mfma_f32_16x16x32_bf16(qf[0][1], kb1, z0, 0, 0, 0);
                z1 = __builtin_amdgcn_mfma_f32_16x16x32_bf16(qf[1][0], kb0, z1, 0, 0, 0);
                z1 = __builtin_amdgcn_mfma_f32_16x16x32_bf16(qf[1][1], kb1, z1, 0, 0, 0);
                s0[c] = z0; s1[c] = z1;
            }

            #pragma unroll
            for (int g = 0; g < 2; g++) {
                const int qrb = wq0 + g * 16;
                f4v* s = g ? s1 : s0;
                if ((kk0 + 63) > qrb) {
                    #pragma unroll
                    for (int c = 0; c < 4; c++) {
                        int kkg = kk0 + c * 16 + llo;
                        #pragma unroll
                        for (int r = 0; r < 4; r++)
                            if (kkg > qrb + lhi * 4 + r) s[c][r] = -1e9f;
                    }
                }
                #pragma unroll
                for (int h = 0; h < 2; h++) {
                    #pragma unroll
                    for (int r = 0; r < 4; r++) {
                        float p0 = __builtin_amdgcn_exp2f(s[2 * h][r]);
                        float p1 = __builtin_amdgcn_exp2f(s[2 * h + 1][r]);
                        lsum[g][r] += p0 + p1;
                        unsigned pk;
                        asm("v_cvt_pk_bf16_f32 %0, %1, %2" : "=v"(pk) : "v"(p0), "v"(p1));
                        *(unsigned*)&Ps[wave][g][h * 640 + (lhi * 4 + r) * 40 + llo * 2] = pk;
                    }
                }
            }

            s8v pa[2][2];
            #pragma unroll
            for (int g = 0; g < 2; g++) {
                pa[g][0] = *(const s8v*)&Ps[wave][g][llo * 40 + lhi * 8];
                pa[g][1] = *(const s8v*)&Ps[wave][g][640 + llo * 40 + lhi * 8];
            }
            #pragma unroll
            for (int cd = 0; cd < 4; cd++) {
                const int rb = (cd * 16 + llo) * 64;
                s8v vb0 = *(const s8v*)&Vts[cur][rb + ((lhi    ) ^ xs) * 8];
                s8v vb1 = *(const s8v*)&Vts[cur][rb + ((4 + lhi) ^ xs) * 8];
                #pragma unroll
                for (int g = 0; g < 2; g++) {
                    o[g][cd] = __builtin_amdgcn_mfma_f32_16x16x32_bf16(pa[g][0], vb0, o[g][cd], 0, 0, 0);
                    o[g][cd] = __builtin_amdgcn_mfma_f32_16x16x32_bf16(pa[g][1], vb1, o[g][cd], 0, 0, 0);
                }
            }
        }

        __syncthreads();
        cur ^= 1;
    }

    #pragma unroll
    for (int off = 1; off < 16; off <<= 1)
        #pragma unroll
        for (int g = 0; g < 2; g++)
            #pragma unroll
            for (int r = 0; r < 4; r++)
                lsum[g][r] += __shfl_xor(lsum[g][r], off, 64);

    #pragma unroll
    for (int g = 0; g < 2; g++)
        #pragma unroll
        for (int cd = 0; cd < 4; cd++)
            #pragma unroll
            for (int r = 0; r < 4; r++) {
                int qq = wq0 + g * 16 + lhi * 4 + r;
                int d  = cd * 16 + llo;
                ao_ws[((size_t)(b * 2048 + qq)) * 1024 + head * 64 + d] =
                    f2bf(o[g][cd][r] / lsum[g][r]);
            }
}

// ---------------------------------------------------------------------------
extern "C" void kernel_launch(void* const* d_in, const int* in_sizes, int n_in,
                              void* d_out, int out_size, void* d_ws, size_t ws_size,
                              hipStream_t stream) {
    const float* x    = (const float*)d_in[0];
    const float* wqkv = (const float*)d_in[1];
    const float* wout = (const float*)d_in[2];

    // ws (bf16 elems): wqkvb 3M | woutb 1M | xb 8M | q 8M | k 8M | vt 8M = 72 MB
    // reuse: v^T <- xb (dead after gemm0); ao <- vt (dead after transpose)
    ushort_t* wqkvb = (ushort_t*)d_ws;
    ushort_t* woutb = wqkvb + 3145728;
    ushort_t* xb    = woutb + 1048576;
    ushort_t* q_ws  = xb + 8388608;
    ushort_t* k_ws  = q_ws + 8388608;
    ushort_t* vt_ws = k_ws + 8388608;     // V t-major [b,h,t,d] from gemm0
    ushort_t* v_ws  = xb;                 // V^T [b,h,d,sigma(t)]
    ushort_t* ao_ws = vt_ws;              // attn output
    float*    out   = (float*)d_out;

    cast_f32_bf16<<<4096, 256, 0, stream>>>(x,    xb,    1048576);
    cast_f32_bf16<<<1536, 256, 0, stream>>>(wqkv, wqkvb, 393216);
    cast_f32_bf16<<< 512, 256, 0, stream>>>(wout, woutb, 131072);
    gemm256_qkv<<<dim3(32, 12), 512, 0, stream>>>(xb, wqkvb, q_ws, k_ws, vt_ws);
    transpose_v<<<dim3(32, 64), 256, 0, stream>>>(vt_ws, v_ws);
    attn_kernel<<<dim3(8, 64), 512, 0, stream>>>(q_ws, k_ws, v_ws, ao_ws);
    gemm_nt<1><<<dim3(64, 8), 256, 0, stream>>>(ao_ws, woutb, nullptr, nullptr, nullptr, out);
}

// Round 8
// 228.651 us; speedup vs baseline: 1.1226x; 1.1226x over previous
//
#include <hip/hip_runtime.h>
#include <hip/hip_bf16.h>

// B=4, T=2048, H=1024, NH=16, HD=64. Inputs FP32, output FP32.
// R17: structural de-glue (7 -> 4 dispatches), proven kernel bodies kept:
//  [a] gemm0 reverted to the 128^2 2-phase kernel (R6: 75.9us; R7's 8-phase
//      256^2 was 85us at 75% grid packing / 23% MfmaUtil -> dropped).
//  [b] 3 cast kernels fused into one range-dispatched cast_all.
//  [c] V transpose + sigma-permutation folded into gemm0's epilogue:
//      V-blocks (n0>=2048, block-uniform) bounce their tile through the
//      idle 32KB staging LDS in two 64-t passes (b64 LDS writes, sigma
//      gather, 16B coalesced V^T stores). transpose_v kernel + its 64MB
//      HBM round-trip deleted.
//  [d] buffers rotated: V^T -> old vt slot (gemm0-written), ao -> xb.

typedef unsigned short ushort_t;
typedef __attribute__((ext_vector_type(8))) short  s8v;
typedef __attribute__((ext_vector_type(4))) float  f4v;
typedef __attribute__((ext_vector_type(4))) unsigned int u4v;

__device__ inline ushort_t f2bf(float f) {
    unsigned u = __builtin_bit_cast(unsigned, f);
    u += 0x7fffu + ((u >> 16) & 1u);   // RNE
    return (ushort_t)(u >> 16);
}

// async global->LDS, 16B per lane; LDS dest must be wave-uniform base + lane*16
__device__ inline void gload16(const ushort_t* g, ushort_t* l) {
    __builtin_amdgcn_global_load_lds(
        (const __attribute__((address_space(1))) unsigned int*)g,
        (__attribute__((address_space(3))) unsigned int*)l, 16, 0, 0);
}

// ---------------------------------------------------------------------------
// Fused cast: x (1048576 n8) | wqkv (393216) | wout (131072). 6144 blocks.
// ---------------------------------------------------------------------------
__global__ __launch_bounds__(256) void cast_all(
    const float* __restrict__ x, const float* __restrict__ wqkv,
    const float* __restrict__ wout, ushort_t* __restrict__ xb,
    ushort_t* __restrict__ wqkvb, ushort_t* __restrict__ woutb)
{
    int i = blockIdx.x * 256 + threadIdx.x;      // 0..1572863, exact
    const float* src; ushort_t* dst; int off;
    if (i < 1048576)      { src = x;    dst = xb;    off = i; }
    else if (i < 1441792) { src = wqkv; dst = wqkvb; off = i - 1048576; }
    else                  { src = wout; dst = woutb; off = i - 1441792; }
    const float* p = src + (size_t)off * 8;
    f4v a = *(const f4v*)p;
    f4v b = *(const f4v*)(p + 4);
    union { u4v v; ushort_t u[8]; } o;
    #pragma unroll
    for (int j = 0; j < 4; j++) { o.u[j] = f2bf(a[j]); o.u[j + 4] = f2bf(b[j]); }
    *(u4v*)(dst + (size_t)off * 8) = o.v;
}

// ---------------------------------------------------------------------------
// GEMM C[M,N] = A[M,K]*B[N,K]^T, K=1024, bf16 MFMA, f32 acc. 128^2, BK=32,
// 2-buffer ping-pong, conflict-free swizzle (row>>1)&3.
// MODE 0: Q scaled + t-major K stores; V tiles transposed+sigma-permuted
//         through LDS in the epilogue (o2 = V^T [b,h,d,sigma(t)]).
// MODE 1: row-major FP32 store.
// ---------------------------------------------------------------------------
template<int MODE>
__global__ __launch_bounds__(256) void gemm_nt(
    const ushort_t* __restrict__ A, const ushort_t* __restrict__ Bm,
    ushort_t* __restrict__ o0, ushort_t* __restrict__ o1, ushort_t* __restrict__ o2,
    float* __restrict__ of)
{
    // staging (main loop): As = SH[0..8191], Bs = SH[8192..16383]
    // epilogue (V blocks): Lt[128][68] = SH[0..8703]
    __shared__ __align__(16) ushort_t SH[16384];

    const int tid  = threadIdx.x;
    const int m0   = blockIdx.x * 128;
    const int n0   = blockIdx.y * 128;
    const int wave = tid >> 6, lane = tid & 63;
    const int wr = wave >> 1, wc = wave & 1;
    const int lhi = lane >> 4, llo = lane & 15;
    const int srow = lane >> 2;
    const int scol = (((lane & 3) ^ ((srow >> 1) & 3)) * 8);

    auto stage = [&](int k0, int buf) {
        #pragma unroll
        for (int p = 0; p < 2; p++) {
            int chunk = wave * 2 + p;                     // 0..7, 16 rows each
            int row = chunk * 16 + srow;
            gload16(A  + (size_t)(m0 + row) * 1024 + k0 + scol,
                    &SH[buf * 4096 + chunk * 512 + lane * 8]);
            gload16(Bm + (size_t)(n0 + row) * 1024 + k0 + scol,
                    &SH[8192 + buf * 4096 + chunk * 512 + lane * 8]);
        }
    };

    f4v acc[4][4] = {};
    int buf = 0;

    stage(0, 0);
    __syncthreads();

    for (int k0 = 0; k0 < 1024; k0 += 32) {
        if (k0 + 32 < 1024) stage(k0 + 32, buf ^ 1);

        const int rch = (lhi ^ ((llo >> 1) & 3)) * 8;
        s8v a[4], b[4];
        #pragma unroll
        for (int i = 0; i < 4; i++)
            a[i] = *(const s8v*)&SH[buf * 4096 + (wr * 64 + i * 16 + llo) * 32 + rch];
        #pragma unroll
        for (int i = 0; i < 4; i++)
            b[i] = *(const s8v*)&SH[8192 + buf * 4096 + (wc * 64 + i * 16 + llo) * 32 + rch];
        #pragma unroll
        for (int i = 0; i < 4; i++)
            #pragma unroll
            for (int j = 0; j < 4; j++)
                acc[i][j] = __builtin_amdgcn_mfma_f32_16x16x32_bf16(a[i], b[j], acc[i][j], 0, 0, 0);

        __syncthreads();
        buf ^= 1;
    }

    if (MODE == 0 && n0 >= 2048) {
        // ---- V tile: transpose + sigma through LDS, coalesced V^T stores ----
        const int hbase = (n0 - 2048) >> 6;      // head base (even)
        const int t0b   = m0 & 2047;
        const int bb    = m0 >> 11;
        #pragma unroll 1
        for (int p = 0; p < 2; p++) {            // t-halves (64 each)
            __syncthreads();                     // LDS free for this pass
            if (wr == p) {
                #pragma unroll
                for (int i = 0; i < 4; i++)
                    #pragma unroll
                    for (int j = 0; j < 4; j++) {
                        union { unsigned long long q; ushort_t u[4]; } w;
                        #pragma unroll
                        for (int r = 0; r < 4; r++) w.u[r] = f2bf(acc[i][j][r]);
                        int nrel = wc * 64 + j * 16 + llo;
                        *(unsigned long long*)&SH[nrel * 68 + i * 16 + lhi * 4] = w.q;
                    }
            }
            __syncthreads();
            #pragma unroll
            for (int cc = 0; cc < 4; cc++) {
                int c  = cc * 256 + tid;         // 0..1023
                int nn = c >> 3, sp0 = (c & 7) * 8;
                union { s8v v; ushort_t u[8]; } o;
                #pragma unroll
                for (int i2 = 0; i2 < 8; i2++) {
                    int sp = sp0 + i2;           // sigma position
                    int k  = ((sp >> 5) << 5) | ((sp & 1) << 4) | ((sp & 31) >> 1);
                    o.u[i2] = SH[nn * 68 + k];
                }
                int head = hbase + (nn >> 6), d = nn & 63;
                size_t bh = (size_t)(bb * 16 + head);
                *(s8v*)(o2 + ((bh * 64 + d) * 2048 + t0b + p * 64 + sp0)) = o.v;
            }
        }
        return;
    }

    #pragma unroll
    for (int i = 0; i < 4; i++) {
        #pragma unroll
        for (int j = 0; j < 4; j++) {
            #pragma unroll
            for (int r = 0; r < 4; r++) {
                int m = m0 + wr * 64 + i * 16 + lhi * 4 + r;
                int n = n0 + wc * 64 + j * 16 + llo;
                if (MODE == 1) {
                    of[(size_t)m * 1024 + n] = acc[i][j][r];
                } else {
                    float val = acc[i][j][r];
                    int b  = m >> 11, t = m & 2047;
                    int which = n >> 10, hh = n & 1023;
                    int head = hh >> 6, d = hh & 63;
                    size_t bh = (size_t)(b * 16 + head);
                    if (which == 0)
                        // Q pre-scaled by 1/sqrt(64)*log2(e) for exp2 softmax
                        o0[(size_t)m * 1024 + hh] = f2bf(val * 0.18033688011112042f);
                    else
                        o1[(bh * 2048 + t) * 64 + d] = f2bf(val);   // K [b,h,t,d]
                }
            }
        }
    }
}

// ---------------------------------------------------------------------------
// Flash attention, causal, exp2 domain, m-free softmax (unchanged from R6).
// Block: waves 0-3 -> q-tile p, waves 4-7 -> q-tile 15-p (32 rows/wave).
// K/V LDS [64][64] XOR-swizzled; P sigma-packed via v_cvt_pk_bf16_f32.
// ---------------------------------------------------------------------------
__global__ __launch_bounds__(512, 4) void attn_kernel(
    const ushort_t* __restrict__ q_ws, const ushort_t* __restrict__ k_ws,
    const ushort_t* __restrict__ v_ws, ushort_t* __restrict__ ao_ws)
{
    const int p    = blockIdx.x;          // 0..7 -> q-tiles (p, 15-p)
    const int bh   = blockIdx.y;
    const int tid  = threadIdx.x;
    const int wave = tid >> 6, lane = tid & 63;
    const int lhi = lane >> 4, llo = lane & 15;
    const int b = bh >> 4, head = bh & 15;

    const ushort_t* Kb = k_ws + (size_t)bh * 2048 * 64;
    const ushort_t* Vb = v_ws + (size_t)bh * 64 * 2048;   // [d][sigma(t)]

    __shared__ __align__(16) ushort_t Ks [2][4096];       // [buf][64 kk][64 d] swz
    __shared__ __align__(16) ushort_t Vts[2][4096];       // [buf][64 d][64 sig] swz
    __shared__ __align__(16) ushort_t Ps [8][2][1280];    // [wave][g][half][16q][40]

    const int srow = wave * 8 + (lane >> 3);              // 0..63
    const int gch  = ((lane & 7) ^ (srow & 7)) * 8;       // pre-swizzled src col
    auto stage = [&](int t, int buf) {
        const int kk0 = t * 64;
        gload16(Kb + (size_t)(kk0 + srow) * 64 + gch,
                &Ks[buf][srow * 64 + (lane & 7) * 8]);
        gload16(Vb + (size_t)srow * 2048 + kk0 + gch,
                &Vts[buf][srow * 64 + (lane & 7) * 8]);
    };

    const int qt  = (wave >> 2) ? (15 - p) : p;           // this wave's q-tile
    const int wq0 = qt * 128 + (wave & 3) * 32;           // wave's 32 q-rows

    s8v qf[2][2];
    #pragma unroll
    for (int g = 0; g < 2; g++) {
        const ushort_t* Qp = q_ws + (size_t)(b * 2048 + wq0 + g * 16 + llo) * 1024 + head * 64;
        qf[g][0] = *(const s8v*)(Qp + lhi * 8);
        qf[g][1] = *(const s8v*)(Qp + 32 + lhi * 8);
    }

    f4v o[2][4] = {};
    float lsum[2][4] = {};

    const int ntb = 32 - 2 * p;           // shared loop length
    const int xs  = llo & 7;
    int cur = 0;

    stage(0, 0);
    __syncthreads();

    #pragma unroll 1
    for (int t = 0; t < ntb; t++) {
        if (t + 1 < ntb) stage(t + 1, cur ^ 1);

        const int kk0 = t * 64;
        if (kk0 <= wq0 + 31) {
            f4v s0[4], s1[4];
            #pragma unroll
            for (int c = 0; c < 4; c++) {
                const int rb = (c * 16 + llo) * 64;
                s8v kb0 = *(const s8v*)&Ks[cur][rb + ((lhi    ) ^ xs) * 8];
                s8v kb1 = *(const s8v*)&Ks[cur][rb + ((4 + lhi) ^ xs) * 8];
                f4v z0 = {}, z1 = {};
                z0 = __builtin_amdgcn_mfma_f32_16x16x32_bf16(qf[0][0], kb0, z0, 0, 0, 0);
                z0 = __builtin_amdgcn_mfma_f32_16x16x32_bf16(qf[0][1], kb1, z0, 0, 0, 0);
                z1 = __builtin_amdgcn_mfma_f32_16x16x32_bf16(qf[1][0], kb0, z1, 0, 0, 0);
                z1 = __builtin_amdgcn_mfma_f32_16x16x32_bf16(qf[1][1], kb1, z1, 0, 0, 0);
                s0[c] = z0; s1[c] = z1;
            }

            #pragma unroll
            for (int g = 0; g < 2; g++) {
                const int qrb = wq0 + g * 16;
                f4v* s = g ? s1 : s0;
                if ((kk0 + 63) > qrb) {
                    #pragma unroll
                    for (int c = 0; c < 4; c++) {
                        int kkg = kk0 + c * 16 + llo;
                        #pragma unroll
                        for (int r = 0; r < 4; r++)
                            if (kkg > qrb + lhi * 4 + r) s[c][r] = -1e9f;
                    }
                }
                #pragma unroll
                for (int h = 0; h < 2; h++) {
                    #pragma unroll
                    for (int r = 0; r < 4; r++) {
                        float p0 = __builtin_amdgcn_exp2f(s[2 * h][r]);
                        float p1 = __builtin_amdgcn_exp2f(s[2 * h + 1][r]);
                        lsum[g][r] += p0 + p1;
                        unsigned pk;
                        asm("v_cvt_pk_bf16_f32 %0, %1, %2" : "=v"(pk) : "v"(p0), "v"(p1));
                        *(unsigned*)&Ps[wave][g][h * 640 + (lhi * 4 + r) * 40 + llo * 2] = pk;
                    }
                }
            }

            s8v pa[2][2];
            #pragma unroll
            for (int g = 0; g < 2; g++) {
                pa[g][0] = *(const s8v*)&Ps[wave][g][llo * 40 + lhi * 8];
                pa[g][1] = *(const s8v*)&Ps[wave][g][640 + llo * 40 + lhi * 8];
            }
            #pragma unroll
            for (int cd = 0; cd < 4; cd++) {
                const int rb = (cd * 16 + llo) * 64;
                s8v vb0 = *(const s8v*)&Vts[cur][rb + ((lhi    ) ^ xs) * 8];
                s8v vb1 = *(const s8v*)&Vts[cur][rb + ((4 + lhi) ^ xs) * 8];
                #pragma unroll
                for (int g = 0; g < 2; g++) {
                    o[g][cd] = __builtin_amdgcn_mfma_f32_16x16x32_bf16(pa[g][0], vb0, o[g][cd], 0, 0, 0);
                    o[g][cd] = __builtin_amdgcn_mfma_f32_16x16x32_bf16(pa[g][1], vb1, o[g][cd], 0, 0, 0);
                }
            }
        }

        __syncthreads();
        cur ^= 1;
    }

    #pragma unroll
    for (int off = 1; off < 16; off <<= 1)
        #pragma unroll
        for (int g = 0; g < 2; g++)
            #pragma unroll
            for (int r = 0; r < 4; r++)
                lsum[g][r] += __shfl_xor(lsum[g][r], off, 64);

    #pragma unroll
    for (int g = 0; g < 2; g++)
        #pragma unroll
        for (int cd = 0; cd < 4; cd++)
            #pragma unroll
            for (int r = 0; r < 4; r++) {
                int qq = wq0 + g * 16 + lhi * 4 + r;
                int d  = cd * 16 + llo;
                ao_ws[((size_t)(b * 2048 + qq)) * 1024 + head * 64 + d] =
                    f2bf(o[g][cd][r] / lsum[g][r]);
            }
}

// ---------------------------------------------------------------------------
extern "C" void kernel_launch(void* const* d_in, const int* in_sizes, int n_in,
                              void* d_out, int out_size, void* d_ws, size_t ws_size,
                              hipStream_t stream) {
    const float* x    = (const float*)d_in[0];
    const float* wqkv = (const float*)d_in[1];
    const float* wout = (const float*)d_in[2];

    // ws (bf16 elems): wqkvb 3M | woutb 1M | xb 8M | q 8M | k 8M | v^T 8M = 72 MB
    // ao <- xb (dead after gemm0); V^T written directly by gemm0 epilogue.
    ushort_t* wqkvb = (ushort_t*)d_ws;
    ushort_t* woutb = wqkvb + 3145728;
    ushort_t* xb    = woutb + 1048576;
    ushort_t* q_ws  = xb + 8388608;
    ushort_t* k_ws  = q_ws + 8388608;
    ushort_t* v_ws  = k_ws + 8388608;     // V^T [b,h,d,sigma(t)]
    ushort_t* ao_ws = xb;                 // attn output
    float*    out   = (float*)d_out;

    cast_all<<<6144, 256, 0, stream>>>(x, wqkv, wout, xb, wqkvb, woutb);
    gemm_nt<0><<<dim3(64, 24), 256, 0, stream>>>(xb, wqkvb, q_ws, k_ws, v_ws, nullptr);
    attn_kernel<<<dim3(8, 64), 512, 0, stream>>>(q_ws, k_ws, v_ws, ao_ws);
    gemm_nt<1><<<dim3(64, 8), 256, 0, stream>>>(ao_ws, woutb, nullptr, nullptr, nullptr, out);
}

// Round 9
// 225.474 us; speedup vs baseline: 1.1384x; 1.0141x over previous
//
#include <hip/hip_runtime.h>
#include <hip/hip_bf16.h>

// B=4, T=2048, H=1024, NH=16, HD=64. Inputs FP32, output FP32.
// R18:
//  [a] gemm BK=32 -> 64 (2-buffer ping-pong kept, static indices): barrier
//      vmcnt(0)-drains halve 32 -> 16 per block. Stage/read use the
//      attn-verified 8-chunk XOR swizzle (phys chunk = logical ^ (row&7)).
//      LDS 64KB -> 2 blocks/CU (was ~2.3).
//  [b] attn CU-balance: co-resident blocks are (x,y),(x,y+32) [x fastest];
//      old px=x paired EQUAL loop lengths (CU totals 36..64 units, 28% tail).
//      Remap px=(bh<32)?x:7-x -> co-resident pair sums uniform ~50 units.
//  [c] attn: s_setprio(1) around QK^T and PV MFMA clusters (T5, attn regime).
// cast_all / epilogue V-transpose / workspace unchanged from R8.

typedef unsigned short ushort_t;
typedef __attribute__((ext_vector_type(8))) short  s8v;
typedef __attribute__((ext_vector_type(4))) float  f4v;
typedef __attribute__((ext_vector_type(4))) unsigned int u4v;

__device__ inline ushort_t f2bf(float f) {
    unsigned u = __builtin_bit_cast(unsigned, f);
    u += 0x7fffu + ((u >> 16) & 1u);   // RNE
    return (ushort_t)(u >> 16);
}

// async global->LDS, 16B per lane; LDS dest must be wave-uniform base + lane*16
__device__ inline void gload16(const ushort_t* g, ushort_t* l) {
    __builtin_amdgcn_global_load_lds(
        (const __attribute__((address_space(1))) unsigned int*)g,
        (__attribute__((address_space(3))) unsigned int*)l, 16, 0, 0);
}

// ---------------------------------------------------------------------------
// Fused cast: x (1048576 n8) | wqkv (393216) | wout (131072). 6144 blocks.
// ---------------------------------------------------------------------------
__global__ __launch_bounds__(256) void cast_all(
    const float* __restrict__ x, const float* __restrict__ wqkv,
    const float* __restrict__ wout, ushort_t* __restrict__ xb,
    ushort_t* __restrict__ wqkvb, ushort_t* __restrict__ woutb)
{
    int i = blockIdx.x * 256 + threadIdx.x;      // 0..1572863, exact
    const float* src; ushort_t* dst; int off;
    if (i < 1048576)      { src = x;    dst = xb;    off = i; }
    else if (i < 1441792) { src = wqkv; dst = wqkvb; off = i - 1048576; }
    else                  { src = wout; dst = woutb; off = i - 1441792; }
    const float* p = src + (size_t)off * 8;
    f4v a = *(const f4v*)p;
    f4v b = *(const f4v*)(p + 4);
    union { u4v v; ushort_t u[8]; } o;
    #pragma unroll
    for (int j = 0; j < 4; j++) { o.u[j] = f2bf(a[j]); o.u[j + 4] = f2bf(b[j]); }
    *(u4v*)(dst + (size_t)off * 8) = o.v;
}

// ---------------------------------------------------------------------------
// GEMM C[M,N] = A[M,K]*B[N,K]^T, K=1024, bf16 MFMA, f32 acc. 128^2, BK=64,
// 2-buffer ping-pong, 8-chunk XOR swizzle (phys chunk = logical ^ (row&7)).
// MODE 0: Q scaled + t-major K stores; V tiles transposed+sigma-permuted
//         through LDS in the epilogue (o2 = V^T [b,h,d,sigma(t)]).
// MODE 1: row-major FP32 store.
// ---------------------------------------------------------------------------
template<int MODE>
__global__ __launch_bounds__(256) void gemm_nt(
    const ushort_t* __restrict__ A, const ushort_t* __restrict__ Bm,
    ushort_t* __restrict__ o0, ushort_t* __restrict__ o1, ushort_t* __restrict__ o2,
    float* __restrict__ of)
{
    // main loop: As = SH[buf*8192 .. +8191], Bs = SH[16384 + buf*8192 ..]
    // epilogue (V blocks): Lt[128][68] = SH[0..8703]
    __shared__ __align__(16) ushort_t SH[32768];   // 64 KiB

    const int tid  = threadIdx.x;
    const int m0   = blockIdx.x * 128;
    const int n0   = blockIdx.y * 128;
    const int wave = tid >> 6, lane = tid & 63;
    const int wr = wave >> 1, wc = wave & 1;
    const int lhi = lane >> 4, llo = lane & 15;
    // stage lane map: 8 rows/issue, 8 chunks of 16B per 128B row
    const int sgch = ((lane & 7) ^ (lane >> 3)) * 8;   // pre-swizzled src col

    auto stage = [&](int k0, int buf) {
        #pragma unroll
        for (int p = 0; p < 4; p++) {
            int row = wave * 32 + p * 8 + (lane >> 3);   // 0..127
            gload16(A  + (size_t)(m0 + row) * 1024 + k0 + sgch,
                    &SH[buf * 8192 + row * 64 + (lane & 7) * 8]);
            gload16(Bm + (size_t)(n0 + row) * 1024 + k0 + sgch,
                    &SH[16384 + buf * 8192 + row * 64 + (lane & 7) * 8]);
        }
    };

    f4v acc[4][4] = {};
    int buf = 0;
    const int xs = llo & 7;                    // read-side XOR (row&7 == llo&7)

    stage(0, 0);
    __syncthreads();

    for (int k0 = 0; k0 < 1024; k0 += 64) {
        if (k0 + 64 < 1024) stage(k0 + 64, buf ^ 1);

        #pragma unroll
        for (int s = 0; s < 2; s++) {
            s8v a[4], b[4];
            #pragma unroll
            for (int i = 0; i < 4; i++)
                a[i] = *(const s8v*)&SH[buf * 8192
                        + (wr * 64 + i * 16 + llo) * 64 + ((s * 4 + lhi) ^ xs) * 8];
            #pragma unroll
            for (int i = 0; i < 4; i++)
                b[i] = *(const s8v*)&SH[16384 + buf * 8192
                        + (wc * 64 + i * 16 + llo) * 64 + ((s * 4 + lhi) ^ xs) * 8];
            #pragma unroll
            for (int i = 0; i < 4; i++)
                #pragma unroll
                for (int j = 0; j < 4; j++)
                    acc[i][j] = __builtin_amdgcn_mfma_f32_16x16x32_bf16(a[i], b[j], acc[i][j], 0, 0, 0);
        }

        __syncthreads();
        buf ^= 1;
    }

    if (MODE == 0 && n0 >= 2048) {
        // ---- V tile: transpose + sigma through LDS, coalesced V^T stores ----
        const int hbase = (n0 - 2048) >> 6;      // head base (even)
        const int t0b   = m0 & 2047;
        const int bb    = m0 >> 11;
        #pragma unroll 1
        for (int p = 0; p < 2; p++) {            // t-halves (64 each)
            __syncthreads();                     // LDS free for this pass
            if (wr == p) {
                #pragma unroll
                for (int i = 0; i < 4; i++)
                    #pragma unroll
                    for (int j = 0; j < 4; j++) {
                        union { unsigned long long q; ushort_t u[4]; } w;
                        #pragma unroll
                        for (int r = 0; r < 4; r++) w.u[r] = f2bf(acc[i][j][r]);
                        int nrel = wc * 64 + j * 16 + llo;
                        *(unsigned long long*)&SH[nrel * 68 + i * 16 + lhi * 4] = w.q;
                    }
            }
            __syncthreads();
            #pragma unroll
            for (int cc = 0; cc < 4; cc++) {
                int c  = cc * 256 + tid;         // 0..1023
                int nn = c >> 3, sp0 = (c & 7) * 8;
                union { s8v v; ushort_t u[8]; } o;
                #pragma unroll
                for (int i2 = 0; i2 < 8; i2++) {
                    int sp = sp0 + i2;           // sigma position
                    int k  = ((sp >> 5) << 5) | ((sp & 1) << 4) | ((sp & 31) >> 1);
                    o.u[i2] = SH[nn * 68 + k];
                }
                int head = hbase + (nn >> 6), d = nn & 63;
                size_t bh = (size_t)(bb * 16 + head);
                *(s8v*)(o2 + ((bh * 64 + d) * 2048 + t0b + p * 64 + sp0)) = o.v;
            }
        }
        return;
    }

    #pragma unroll
    for (int i = 0; i < 4; i++) {
        #pragma unroll
        for (int j = 0; j < 4; j++) {
            #pragma unroll
            for (int r = 0; r < 4; r++) {
                int m = m0 + wr * 64 + i * 16 + lhi * 4 + r;
                int n = n0 + wc * 64 + j * 16 + llo;
                if (MODE == 1) {
                    of[(size_t)m * 1024 + n] = acc[i][j][r];
                } else {
                    float val = acc[i][j][r];
                    int b  = m >> 11, t = m & 2047;
                    int which = n >> 10, hh = n & 1023;
                    int head = hh >> 6, d = hh & 63;
                    size_t bh = (size_t)(b * 16 + head);
                    if (which == 0)
                        // Q pre-scaled by 1/sqrt(64)*log2(e) for exp2 softmax
                        o0[(size_t)m * 1024 + hh] = f2bf(val * 0.18033688011112042f);
                    else
                        o1[(bh * 2048 + t) * 64 + d] = f2bf(val);   // K [b,h,t,d]
                }
            }
        }
    }
}

// ---------------------------------------------------------------------------
// Flash attention, causal, exp2 domain, m-free softmax.
// px = (bh<32) ? x : 7-x balances co-resident (x,y),(x,y+32) block pairs.
// Waves 0-3 -> q-tile px, waves 4-7 -> 15-px (32 rows/wave); shared KV loop.
// K/V LDS [64][64] XOR-swizzled; P sigma-packed via v_cvt_pk_bf16_f32.
// s_setprio(1) wraps the MFMA clusters (T5).
// ---------------------------------------------------------------------------
__global__ __launch_bounds__(512, 4) void attn_kernel(
    const ushort_t* __restrict__ q_ws, const ushort_t* __restrict__ k_ws,
    const ushort_t* __restrict__ v_ws, ushort_t* __restrict__ ao_ws)
{
    const int bh   = blockIdx.y;
    const int p    = (bh < 32) ? blockIdx.x : 7 - blockIdx.x;   // balanced pair idx
    const int tid  = threadIdx.x;
    const int wave = tid >> 6, lane = tid & 63;
    const int lhi = lane >> 4, llo = lane & 15;
    const int b = bh >> 4, head = bh & 15;

    const ushort_t* Kb = k_ws + (size_t)bh * 2048 * 64;
    const ushort_t* Vb = v_ws + (size_t)bh * 64 * 2048;   // [d][sigma(t)]

    __shared__ __align__(16) ushort_t Ks [2][4096];       // [buf][64 kk][64 d] swz
    __shared__ __align__(16) ushort_t Vts[2][4096];       // [buf][64 d][64 sig] swz
    __shared__ __align__(16) ushort_t Ps [8][2][1280];    // [wave][g][half][16q][40]

    const int srow = wave * 8 + (lane >> 3);              // 0..63
    const int gch  = ((lane & 7) ^ (srow & 7)) * 8;       // pre-swizzled src col
    auto stage = [&](int t, int buf) {
        const int kk0 = t * 64;
        gload16(Kb + (size_t)(kk0 + srow) * 64 + gch,
                &Ks[buf][srow * 64 + (lane & 7) * 8]);
        gload16(Vb + (size_t)srow * 2048 + kk0 + gch,
                &Vts[buf][srow * 64 + (lane & 7) * 8]);
    };

    const int qt  = (wave >> 2) ? (15 - p) : p;           // this wave's q-tile
    const int wq0 = qt * 128 + (wave & 3) * 32;           // wave's 32 q-rows

    s8v qf[2][2];
    #pragma unroll
    for (int g = 0; g < 2; g++) {
        const ushort_t* Qp = q_ws + (size_t)(b * 2048 + wq0 + g * 16 + llo) * 1024 + head * 64;
        qf[g][0] = *(const s8v*)(Qp + lhi * 8);
        qf[g][1] = *(const s8v*)(Qp + 32 + lhi * 8);
    }

    f4v o[2][4] = {};
    float lsum[2][4] = {};

    const int ntb = 32 - 2 * p;           // shared loop length
    const int xs  = llo & 7;
    int cur = 0;

    stage(0, 0);
    __syncthreads();

    #pragma unroll 1
    for (int t = 0; t < ntb; t++) {
        if (t + 1 < ntb) stage(t + 1, cur ^ 1);

        const int kk0 = t * 64;
        if (kk0 <= wq0 + 31) {
            f4v s0[4], s1[4];
            __builtin_amdgcn_s_setprio(1);
            #pragma unroll
            for (int c = 0; c < 4; c++) {
                const int rb = (c * 16 + llo) * 64;
                s8v kb0 = *(const s8v*)&Ks[cur][rb + ((lhi    ) ^ xs) * 8];
                s8v kb1 = *(const s8v*)&Ks[cur][rb + ((4 + lhi) ^ xs) * 8];
                f4v z0 = {}, z1 = {};
                z0 = __builtin_amdgcn_mfma_f32_16x16x32_bf16(qf[0][0], kb0, z0, 0, 0, 0);
                z0 = __builtin_amdgcn_mfma_f32_16x16x32_bf16(qf[0][1], kb1, z0, 0, 0, 0);
                z1 = __builtin_amdgcn_mfma_f32_16x16x32_bf16(qf[1][0], kb0, z1, 0, 0, 0);
                z1 = __builtin_amdgcn_mfma_f32_16x16x32_bf16(qf[1][1], kb1, z1, 0, 0, 0);
                s0[c] = z0; s1[c] = z1;
            }
            __builtin_amdgcn_s_setprio(0);

            #pragma unroll
            for (int g = 0; g < 2; g++) {
                const int qrb = wq0 + g * 16;
                f4v* s = g ? s1 : s0;
                if ((kk0 + 63) > qrb) {
                    #pragma unroll
                    for (int c = 0; c < 4; c++) {
                        int kkg = kk0 + c * 16 + llo;
                        #pragma unroll
                        for (int r = 0; r < 4; r++)
                            if (kkg > qrb + lhi * 4 + r) s[c][r] = -1e9f;
                    }
                }
                #pragma unroll
                for (int h = 0; h < 2; h++) {
                    #pragma unroll
                    for (int r = 0; r < 4; r++) {
                        float p0 = __builtin_amdgcn_exp2f(s[2 * h][r]);
                        float p1 = __builtin_amdgcn_exp2f(s[2 * h + 1][r]);
                        lsum[g][r] += p0 + p1;
                        unsigned pk;
                        asm("v_cvt_pk_bf16_f32 %0, %1, %2" : "=v"(pk) : "v"(p0), "v"(p1));
                        *(unsigned*)&Ps[wave][g][h * 640 + (lhi * 4 + r) * 40 + llo * 2] = pk;
                    }
                }
            }

            s8v pa[2][2];
            #pragma unroll
            for (int g = 0; g < 2; g++) {
                pa[g][0] = *(const s8v*)&Ps[wave][g][llo * 40 + lhi * 8];
                pa[g][1] = *(const s8v*)&Ps[wave][g][640 + llo * 40 + lhi * 8];
            }
            __builtin_amdgcn_s_setprio(1);
            #pragma unroll
            for (int cd = 0; cd < 4; cd++) {
                const int rb = (cd * 16 + llo) * 64;
                s8v vb0 = *(const s8v*)&Vts[cur][rb + ((lhi    ) ^ xs) * 8];
                s8v vb1 = *(const s8v*)&Vts[cur][rb + ((4 + lhi) ^ xs) * 8];
                #pragma unroll
                for (int g = 0; g < 2; g++) {
                    o[g][cd] = __builtin_amdgcn_mfma_f32_16x16x32_bf16(pa[g][0], vb0, o[g][cd], 0, 0, 0);
                    o[g][cd] = __builtin_amdgcn_mfma_f32_16x16x32_bf16(pa[g][1], vb1, o[g][cd], 0, 0, 0);
                }
            }
            __builtin_amdgcn_s_setprio(0);
        }

        __syncthreads();
        cur ^= 1;
    }

    #pragma unroll
    for (int off = 1; off < 16; off <<= 1)
        #pragma unroll
        for (int g = 0; g < 2; g++)
            #pragma unroll
            for (int r = 0; r < 4; r++)
                lsum[g][r] += __shfl_xor(lsum[g][r], off, 64);

    #pragma unroll
    for (int g = 0; g < 2; g++)
        #pragma unroll
        for (int cd = 0; cd < 4; cd++)
            #pragma unroll
            for (int r = 0; r < 4; r++) {
                int qq = wq0 + g * 16 + lhi * 4 + r;
                int d  = cd * 16 + llo;
                ao_ws[((size_t)(b * 2048 + qq)) * 1024 + head * 64 + d] =
                    f2bf(o[g][cd][r] / lsum[g][r]);
            }
}

// ---------------------------------------------------------------------------
extern "C" void kernel_launch(void* const* d_in, const int* in_sizes, int n_in,
                              void* d_out, int out_size, void* d_ws, size_t ws_size,
                              hipStream_t stream) {
    const float* x    = (const float*)d_in[0];
    const float* wqkv = (const float*)d_in[1];
    const float* wout = (const float*)d_in[2];

    // ws (bf16 elems): wqkvb 3M | woutb 1M | xb 8M | q 8M | k 8M | v^T 8M = 72 MB
    // ao <- xb (dead after gemm0); V^T written directly by gemm0 epilogue.
    ushort_t* wqkvb = (ushort_t*)d_ws;
    ushort_t* woutb = wqkvb + 3145728;
    ushort_t* xb    = woutb + 1048576;
    ushort_t* q_ws  = xb + 8388608;
    ushort_t* k_ws  = q_ws + 8388608;
    ushort_t* v_ws  = k_ws + 8388608;     // V^T [b,h,d,sigma(t)]
    ushort_t* ao_ws = xb;                 // attn output
    float*    out   = (float*)d_out;

    cast_all<<<6144, 256, 0, stream>>>(x, wqkv, wout, xb, wqkvb, woutb);
    gemm_nt<0><<<dim3(64, 24), 256, 0, stream>>>(xb, wqkvb, q_ws, k_ws, v_ws, nullptr);
    attn_kernel<<<dim3(8, 64), 512, 0, stream>>>(q_ws, k_ws, v_ws, ao_ws);
    gemm_nt<1><<<dim3(64, 8), 256, 0, stream>>>(ao_ws, woutb, nullptr, nullptr, nullptr, out);
}